// Round 19
// baseline (47.173 us; speedup 1.0000x reference)
//
#include <hip/hip_runtime.h>

// Problem constants (B=8, C=128, H=W=48 -> N=2304)
#define NTOK 2304
#define CC   128

typedef __attribute__((ext_vector_type(8))) short bf16x8;
typedef __attribute__((ext_vector_type(4))) float f32x4;

// round-to-nearest-even fp32 -> bf16
__device__ __forceinline__ unsigned f2bf(float f) {
  unsigned u = __builtin_bit_cast(unsigned, f);
  u += 0x7FFFu + ((u >> 16) & 1u);
  return (u >> 16) & 0xFFFFu;
}
__device__ __forceinline__ unsigned pk2(float a, float b) {
  return f2bf(a) | (f2bf(b) << 16);
}

// async global->LDS, 16B per lane; LDS dest = wave-uniform base + lane*16,
// global src per-lane (guide §5 / m97; size must be literal 16)
__device__ __forceinline__ void g2l16(const void* g, void* l) {
  __builtin_amdgcn_global_load_lds(
      (const __attribute__((address_space(1))) unsigned int*)g,
      (__attribute__((address_space(3))) unsigned int*)l, 16, 0, 0);
}

// Prep (R13, validated): ONE pass over x,y; exact fp32 norms (sx from x,
// sy from y; reference quirk: P[i][j] = ||x_i||^2 + ||y_j||^2 - 2*y_i.x_j)
// AND bf16 "LDS image": img[b][n] = 256 B row of K-contiguous bf16, slot
// swizzle slot=(k>>3)^(n&15)^((n>>4)&3) pre-applied (gemm reads recompute
// absolute-n XOR terms where tile alignment requires).
__global__ __launch_bounds__(256) void pwd_prep(
    const float* __restrict__ x, const float* __restrict__ y,
    char* __restrict__ imgX, char* __restrict__ imgY,
    float* __restrict__ sx, float* __restrict__ sy) {
  __shared__ float part[8][32];
  const int tid = threadIdx.x;
  const int nl  = tid & 31;            // token within 32-chunk
  const int cg  = tid >> 5;            // k-group 0..7 (16 k's = 2 octets)
  const int n   = blockIdx.x * 32 + nl;
  const int b   = blockIdx.y;
  const int sel = blockIdx.z;
  const float* src = sel ? y : x;
  char* img = sel ? imgY : imgX;

  const float* p = src + ((size_t)b * CC + cg * 16) * NTOK + n;
  float v[16];
#pragma unroll
  for (int k = 0; k < 16; ++k) v[k] = p[(size_t)k * NTOK];

  float s = 0.f;
#pragma unroll
  for (int k = 0; k < 16; ++k) s = fmaf(v[k], v[k], s);
  part[cg][nl] = s;

  char* row = img + ((size_t)b * NTOK + n) * 256;
  const int swz = (n & 15) ^ ((n >> 4) & 3);
#pragma unroll
  for (int oo = 0; oo < 2; ++oo) {
    const int o = cg * 2 + oo;         // k-octet 0..15
    uint4 wv;
    wv.x = pk2(v[oo * 8 + 0], v[oo * 8 + 1]);
    wv.y = pk2(v[oo * 8 + 2], v[oo * 8 + 3]);
    wv.z = pk2(v[oo * 8 + 4], v[oo * 8 + 5]);
    wv.w = pk2(v[oo * 8 + 6], v[oo * 8 + 7]);
    *(uint4*)(row + ((o ^ swz) * 16)) = wv;
  }
  __syncthreads();
  if (tid < 32) {
    float t = 0.f;
#pragma unroll
    for (int g = 0; g < 8; ++g) t += part[g][tid];
    (sel ? sy : sx)[b * NTOK + blockIdx.x * 32 + tid] = t;
  }
}

// Main GEMM: 32i x 64j tile, 24 KB LDS -> 6 blocks/CU (24 waves/CU) --
// pushing the proven slot-count/quantum-size lever past R13's 5 slots.
// 256 thr / 4 waves in 2x2 (wave tile 16i x 32j). Staging = 6x
// global_load_lds dwordx4/thread. Epilogue: swizzled LDS bounce ->
// 4-row x 256B-run NT stores (lever (b) preserved: j-width 64 minimum).
//   D[m=j][n=i] = sum_k x[k][j]*y[k][i]  (= y_i . x_j)
__global__ __launch_bounds__(256, 6) void pwd_gemm(
    const char* __restrict__ imgX, const char* __restrict__ imgY,
    const float* __restrict__ sx, const float* __restrict__ sy,
    float* __restrict__ out) {
  __shared__ __attribute__((aligned(16))) char smem[24576];
  char* const smX = smem;            // x panel: 64 j-rows * 256 B (16 KB)
  char* const smY = smem + 16384;    // y panel: 32 i-rows * 256 B ( 8 KB)

  const int tid = threadIdx.x;

  // XCD swizzle: grid 20736 = 8*2592; bid%8 = batch (one batch per XCD L2).
  const int bid = blockIdx.x;
  const int b   = bid & 7;
  const int rem = bid >> 3;            // 0..2591
  const int byy = rem / 36;            // 0..71
  const int bxx = rem - byy * 36;      // 0..35
  const int i0 = byy * 32;             // output rows (i), 32-aligned
  const int j0 = bxx * 64;             // output cols (j), 64-aligned

  const int w  = tid >> 6;             // wave 0..3
  const int l  = tid & 63;
  const int lr = l & 15;
  const int lg = l >> 4;
  const int wi = (w & 1) * 16;         // wave i band (2 x 16)
  const int wj = (w >> 1) * 32;        // wave j band (2 x 32)

  // y-panel swizzle correction: i0 only 32-aligned (R12-verified pattern).
  const int iswz = (i0 >> 4) & 3;

  // ---------------- stage panels via async DMA ------------------------------
  {
    const char* gx = imgX + ((size_t)b * NTOK + j0) * 256;   // 16 KB
    const char* gy = imgY + ((size_t)b * NTOK + i0) * 256;   //  8 KB
    const int o0 = tid * 16;
#pragma unroll
    for (int it = 0; it < 4; ++it)
      g2l16(gx + o0 + it * 4096, smX + o0 + it * 4096);
#pragma unroll
    for (int it = 0; it < 2; ++it)
      g2l16(gy + o0 + it * 4096, smY + o0 + it * 4096);
  }

  // ---------------- hoist norms into registers (in flight over DMA) ---------
  const float sxr = sx[b * NTOK + i0 + wi + lr];        // x norm at row i
  f32x4 syq[2];
#pragma unroll
  for (int mf = 0; mf < 2; ++mf)                         // y norms at j quad
    syq[mf] = *(const f32x4*)(sy + b * NTOK + j0 + wj + mf * 16 + lg * 4);

  __syncthreads();   // drains vmcnt (DMA complete)

  // ---------------- compute: wave tile 32j x 16i ----------------------------
  f32x4 acc[2] = {};
#pragma unroll
  for (int ks = 0; ks < 4; ++ks) {
    const int o = ks * 4 + lg;           // 16B slot (8 k's)
    bf16x8 ax[2], by;
#pragma unroll
    for (int mf = 0; mf < 2; ++mf) {     // A-frag rows = j (j0 64-aligned)
      const int n = wj + mf * 16 + lr;
      const int slot = o ^ (n & 15) ^ ((n >> 4) & 3);
      ax[mf] = *(const bf16x8*)(smX + n * 256 + slot * 16);
    }
    {                                    // B-frag rows = i (absolute swizzle)
      const int n = wi + lr;
      const int slot = o ^ (n & 15) ^ (((n >> 4) + iswz) & 3);
      by = *(const bf16x8*)(smY + n * 256 + slot * 16);
    }
#pragma unroll
    for (int mf = 0; mf < 2; ++mf)
      acc[mf] = __builtin_amdgcn_mfma_f32_16x16x32_bf16(ax[mf], by, acc[mf],
                                                        0, 0, 0);
  }

  // ---------------- epilogue: LDS bounce -> 256B-run NT stores --------------
  // tile[32][64] fp32 (8 KB), 16B chunks XOR-swizzled: chunk addr =
  // row*256 + ((c16 ^ (row&15))*16). Write: 16 rows x 4 c16 per instr
  // (same shape as R13, conflict-free). Read: 4 rows x 16 c16, 2-way free.
  {
    float* const tile = (float*)smem;    // panels dead after compute
    __syncthreads();
#pragma unroll
    for (int mf = 0; mf < 2; ++mf) {
      f32x4 vv;
#pragma unroll
      for (int r = 0; r < 4; ++r)
        vv[r] = sxr + syq[mf][r] - 2.0f * acc[mf][r];
      const int row = wi + lr;                       // local i (0..31)
      const int c16 = (wj >> 2) + mf * 4 + lg;       // 16B chunk (0..15)
      *(f32x4*)((char*)tile + row * 256 + ((c16 ^ (row & 15)) * 16)) = vv;
    }
    __syncthreads();
    // stream out: instr = 64 consecutive 16B chunks = 4 rows x 256 B contig
#pragma unroll
    for (int it = 0; it < 2; ++it) {
      const int c   = it * 256 + tid;    // chunk id 0..511
      const int row = c >> 4;
      const int c16 = c & 15;
      f32x4 vv = *(const f32x4*)((char*)tile + row * 256 +
                                 ((c16 ^ (row & 15)) * 16));
      __builtin_nontemporal_store(
          vv, (f32x4*)(out + ((size_t)b * NTOK + i0 + row) * NTOK + j0 + c16 * 4));
    }
  }
}

extern "C" void kernel_launch(void* const* d_in, const int* in_sizes, int n_in,
                              void* d_out, int out_size, void* d_ws, size_t ws_size,
                              hipStream_t stream) {
  (void)in_sizes; (void)n_in; (void)out_size; (void)ws_size;
  const float* x = (const float*)d_in[0];
  const float* y = (const float*)d_in[1];
  float* out = (float*)d_out;

  // workspace layout: bf16 images (2 x 4.72 MB) + norms (2 x 73.7 KB)
  char* imgX = (char*)d_ws;
  char* imgY = imgX + (size_t)8 * NTOK * 256;
  float* sx  = (float*)(imgY + (size_t)8 * NTOK * 256);
  float* sy  = sx + 8 * NTOK;

  dim3 gp(NTOK / 32, 8, 2);              // 1152 blocks
  pwd_prep<<<gp, dim3(256), 0, stream>>>(x, y, imgX, imgY, sx, sy);

  dim3 gg(72 * 36 * 8);                  // one 32x64 tile per block
  pwd_gemm<<<gg, dim3(256), 0, stream>>>(imgX, imgY, sx, sy, out);
}

// Round 20
// 43.242 us; speedup vs baseline: 1.0909x; 1.0909x over previous
//
#include <hip/hip_runtime.h>

// Problem constants (B=8, C=128, H=W=48 -> N=2304)
#define NTOK 2304
#define CC   128

typedef __attribute__((ext_vector_type(8))) short bf16x8;
typedef __attribute__((ext_vector_type(4))) float f32x4;

// round-to-nearest-even fp32 -> bf16
__device__ __forceinline__ unsigned f2bf(float f) {
  unsigned u = __builtin_bit_cast(unsigned, f);
  u += 0x7FFFu + ((u >> 16) & 1u);
  return (u >> 16) & 0xFFFFu;
}
__device__ __forceinline__ unsigned pk2(float a, float b) {
  return f2bf(a) | (f2bf(b) << 16);
}

// async global->LDS, 16B per lane; LDS dest = wave-uniform base + lane*16,
// global src per-lane (guide §5 / m97; size must be literal 16)
__device__ __forceinline__ void g2l16(const void* g, void* l) {
  __builtin_amdgcn_global_load_lds(
      (const __attribute__((address_space(1))) unsigned int*)g,
      (__attribute__((address_space(3))) unsigned int*)l, 16, 0, 0);
}

// Prep (best measured, R13/R18): ONE pass over x,y; exact fp32 norms (sx
// from x, sy from y; reference quirk: P[i][j] = ||x_i||^2 + ||y_j||^2 -
// 2*y_i.x_j) AND bf16 "LDS image": img[b][n] = 256 B row of K-contiguous
// bf16, slot swizzle slot=(k>>3)^(n&15)^((n>>4)&3) pre-applied.
__global__ __launch_bounds__(256) void pwd_prep(
    const float* __restrict__ x, const float* __restrict__ y,
    char* __restrict__ imgX, char* __restrict__ imgY,
    float* __restrict__ sx, float* __restrict__ sy) {
  __shared__ float part[8][32];
  const int tid = threadIdx.x;
  const int nl  = tid & 31;            // token within 32-chunk
  const int cg  = tid >> 5;            // k-group 0..7 (16 k's = 2 octets)
  const int n   = blockIdx.x * 32 + nl;
  const int b   = blockIdx.y;
  const int sel = blockIdx.z;
  const float* src = sel ? y : x;
  char* img = sel ? imgY : imgX;

  const float* p = src + ((size_t)b * CC + cg * 16) * NTOK + n;
  float v[16];
#pragma unroll
  for (int k = 0; k < 16; ++k) v[k] = p[(size_t)k * NTOK];

  float s = 0.f;
#pragma unroll
  for (int k = 0; k < 16; ++k) s = fmaf(v[k], v[k], s);
  part[cg][nl] = s;

  char* row = img + ((size_t)b * NTOK + n) * 256;
  const int swz = (n & 15) ^ ((n >> 4) & 3);
#pragma unroll
  for (int oo = 0; oo < 2; ++oo) {
    const int o = cg * 2 + oo;         // k-octet 0..15
    uint4 wv;
    wv.x = pk2(v[oo * 8 + 0], v[oo * 8 + 1]);
    wv.y = pk2(v[oo * 8 + 2], v[oo * 8 + 3]);
    wv.z = pk2(v[oo * 8 + 4], v[oo * 8 + 5]);
    wv.w = pk2(v[oo * 8 + 6], v[oo * 8 + 7]);
    *(uint4*)(row + ((o ^ swz) * 16)) = wv;
  }
  __syncthreads();
  if (tid < 32) {
    float t = 0.f;
#pragma unroll
    for (int g = 0; g < 8; ++g) t += part[g][tid];
    (sel ? sy : sx)[b * NTOK + blockIdx.x * 32 + tid] = t;
  }
}

// Main GEMM (R13/R18, best measured = 42.55 us): 64x64 tile, 256 thr / 4
// waves, LDS 32KB -> 5 blocks/CU (20 waves/CU, decorrelated block phases).
// Staging = 8x global_load_lds dwordx4/thread from pre-swizzled bf16 image.
// Epilogue: LDS bounce (swizzled, conflict-free) -> 4-row x 256B-run NT
// stores. Batch-per-XCD block mapping for L2-resident image panels.
//   D[m=j][n=i] = sum_k x[k][j]*y[k][i]  (= y_i . x_j)
__global__ __launch_bounds__(256, 5) void pwd_gemm(
    const char* __restrict__ imgX, const char* __restrict__ imgY,
    const float* __restrict__ sx, const float* __restrict__ sy,
    float* __restrict__ out) {
  __shared__ __attribute__((aligned(16))) char smem[32768];
  char* const smX = smem;            // x panel: 64 j-rows * 256 B
  char* const smY = smem + 16384;    // y panel: 64 i-rows * 256 B

  const int tid = threadIdx.x;

  // XCD swizzle: grid 10368 = 8*1296; bid%8 = batch (one batch per XCD L2).
  const int bid = blockIdx.x;
  const int b   = bid & 7;
  const int rem = bid >> 3;            // 0..1295
  const int byy = rem / 36;
  const int bxx = rem - byy * 36;
  const int i0 = byy * 64;             // output rows (i)
  const int j0 = bxx * 64;             // output cols (j)

  const int w  = tid >> 6;             // wave 0..3
  const int l  = tid & 63;
  const int lr = l & 15;
  const int lg = l >> 4;
  const int wi = w * 16;               // wave i band

  // ---------------- stage panels via async DMA ------------------------------
  // wave w copies 4KB chunk w of each 16KB panel (4 x 1KB instructions).
  {
    const char* gx = imgX + ((size_t)b * NTOK + j0) * 256;
    const char* gy = imgY + ((size_t)b * NTOK + i0) * 256;
    const int wb = w * 4096;
    const size_t o0 = (size_t)wb + (size_t)l * 16;
#pragma unroll
    for (int it = 0; it < 4; ++it)
      g2l16(gx + o0 + it * 1024, smX + wb + it * 1024);
#pragma unroll
    for (int it = 0; it < 4; ++it)
      g2l16(gy + o0 + it * 1024, smY + wb + it * 1024);
  }

  // ---------------- hoist norms into registers (in flight over DMA) ---------
  const float sxr = sx[b * NTOK + i0 + wi + lr];        // x norm at row i
  f32x4 syq[4];
#pragma unroll
  for (int mf = 0; mf < 4; ++mf)                         // y norms at j quad
    syq[mf] = *(const f32x4*)(sy + b * NTOK + j0 + mf * 16 + lg * 4);

  __syncthreads();   // drains vmcnt (DMA complete)

  // ---------------- compute: wave tile 64j x 16i ----------------------------
  f32x4 acc[4] = {};
#pragma unroll
  for (int ks = 0; ks < 4; ++ks) {
    const int o = ks * 4 + lg;           // 16B slot (8 k's)
    bf16x8 ax[4], by;
#pragma unroll
    for (int mf = 0; mf < 4; ++mf) {     // A-frag rows = j
      const int n = mf * 16 + lr;
      const int slot = o ^ (n & 15) ^ ((n >> 4) & 3);
      ax[mf] = *(const bf16x8*)(smX + n * 256 + slot * 16);
    }
    {                                    // B-frag rows = i
      const int n = wi + lr;
      const int slot = o ^ (n & 15) ^ ((n >> 4) & 3);
      by = *(const bf16x8*)(smY + n * 256 + slot * 16);
    }
#pragma unroll
    for (int mf = 0; mf < 4; ++mf)
      acc[mf] = __builtin_amdgcn_mfma_f32_16x16x32_bf16(ax[mf], by, acc[mf],
                                                        0, 0, 0);
  }

  // ---------------- epilogue: LDS bounce -> 256B-run NT stores --------------
  // tile[64][64] fp32 (16 KB), 16B chunks XOR-swizzled: chunk addr =
  // row*256 + ((c16 ^ (row&15))*16). Both bounce write and read are <=2-way
  // bank aliased (free).
  {
    float* const tile = (float*)smem;    // panels dead after compute
    __syncthreads();
#pragma unroll
    for (int mf = 0; mf < 4; ++mf) {
      f32x4 vv;
#pragma unroll
      for (int r = 0; r < 4; ++r)
        vv[r] = sxr + syq[mf][r] - 2.0f * acc[mf][r];
      const int row = wi + lr;           // local i
      const int c16 = mf * 4 + lg;       // 16B chunk within row (local j/4)
      *(f32x4*)((char*)tile + row * 256 + ((c16 ^ (row & 15)) * 16)) = vv;
    }
    __syncthreads();
    // stream out: instr = 64 consecutive 16B chunks = 4 rows x 256 B contig
#pragma unroll
    for (int it = 0; it < 4; ++it) {
      const int c   = it * 256 + tid;    // chunk id 0..1023
      const int row = c >> 4;
      const int c16 = c & 15;
      f32x4 vv = *(const f32x4*)((char*)tile + row * 256 +
                                 ((c16 ^ (row & 15)) * 16));
      __builtin_nontemporal_store(
          vv, (f32x4*)(out + ((size_t)b * NTOK + i0 + row) * NTOK + j0 + c16 * 4));
    }
  }
}

extern "C" void kernel_launch(void* const* d_in, const int* in_sizes, int n_in,
                              void* d_out, int out_size, void* d_ws, size_t ws_size,
                              hipStream_t stream) {
  (void)in_sizes; (void)n_in; (void)out_size; (void)ws_size;
  const float* x = (const float*)d_in[0];
  const float* y = (const float*)d_in[1];
  float* out = (float*)d_out;

  // workspace layout: bf16 images (2 x 4.72 MB) + norms (2 x 73.7 KB)
  char* imgX = (char*)d_ws;
  char* imgY = imgX + (size_t)8 * NTOK * 256;
  float* sx  = (float*)(imgY + (size_t)8 * NTOK * 256);
  float* sy  = sx + 8 * NTOK;

  dim3 gp(NTOK / 32, 8, 2);              // 1152 blocks
  pwd_prep<<<gp, dim3(256), 0, stream>>>(x, y, imgX, imgY, sx, sy);

  dim3 gg(36 * 36 * 8);                  // one 64x64 tile per block
  pwd_gemm<<<gg, dim3(256), 0, stream>>>(imgX, imgY, sx, sy, out);
}